// Round 27
// baseline (68.739 us; speedup 1.0000x reference)
//
#include <hip/hip_runtime.h>
#include <hip/hip_fp8.h>

typedef float  float4_t __attribute__((ext_vector_type(4)));
typedef unsigned int uint2_t __attribute__((ext_vector_type(2)));
typedef float  f32x4   __attribute__((ext_vector_type(4)));

#define FEAT   256
#define BANK   2048
#define NROWS  2048       // 256 anchors * 8 views
#define NPAN   576        // 64-col panels over 36864 cols
#define NSLOT2 144        // 4-panel slots (class-aligned: 32 % 4 == 0)
#define NCLS   18
#define CSPLIT 16         // m-chunks per class for csum atomics
#define EXP2K  14.4269504088896f   // 10*log2(e); A pre-scaled -> exp(10 dot)=exp2(acc)
#define A_CH8  65536      // A 8-byte chunks: 32 64-row strips * 4 mi * 8 ks * 64 lanes
#define B_CH8  1179648    // B 8-byte chunks: 576 panels * 32 frags * 64 lanes
#define TOT8   (A_CH8 + B_CH8)

// 16-lane (DPP row) sum: every lane of each 16-lane group gets the group total.
__device__ inline float rowsum16(float x) {
    float t;
    asm("s_nop 1\n\tv_add_f32 %0, %1, %1 row_ror:1"  : "=v"(t) : "v"(x)); x = t;
    asm("s_nop 1\n\tv_add_f32 %0, %1, %1 row_ror:2"  : "=v"(t) : "v"(x)); x = t;
    asm("s_nop 1\n\tv_add_f32 %0, %1, %1 row_ror:4"  : "=v"(t) : "v"(x)); x = t;
    asm("s_nop 1\n\tv_add_f32 %0, %1, %1 row_ror:8"  : "=v"(t) : "v"(x)); x = t;
    return x;
}

// HW fp8 pair conversion: packs 8 floats -> 8 e4m3 bytes in 4 instructions.
__device__ inline uint2_t pack8_fp8(float4_t v0, float4_t v1, float scale) {
    int w0 = __builtin_amdgcn_cvt_pk_fp8_f32(v0.x * scale, v0.y * scale, 0, false);
    w0     = __builtin_amdgcn_cvt_pk_fp8_f32(v0.z * scale, v0.w * scale, w0, true);
    int w1 = __builtin_amdgcn_cvt_pk_fp8_f32(v1.x * scale, v1.y * scale, 0, false);
    w1     = __builtin_amdgcn_cvt_pk_fp8_f32(v1.z * scale, v1.w * scale, w1, true);
    uint2_t u = { (unsigned int)w0, (unsigned int)w1 };
    return u;
}

// Pass 0: fp32 -> fp8 e4m3 ONCE via v_cvt_pk_fp8_f32 (HW), MFMA fragment
// order; A pre-scaled by EXP2K (64-row strips). Zeroes out[0] and csum inline.
__global__ __launch_bounds__(256) void pass0_pack(
    const float* __restrict__ X,    // X_anchor [256][8][256]
    const float* __restrict__ Q,    // queue [19][2048][256]
    unsigned char* __restrict__ Abuf,
    unsigned char* __restrict__ Bbuf,
    float* __restrict__ csum,
    float* __restrict__ out)
{
    const int cid = blockIdx.x * 256 + threadIdx.x;
    if (cid == 0) out[0] = 0.0f;
    if (cid < NCLS * FEAT) csum[cid] = 0.0f;
    if (cid >= TOT8) return;
    const int lane = cid & 63;
    const int ks   = (cid >> 6) & 7;
    const int k    = ks * 32 + ((lane >> 4) << 3);
    const float* src;
    unsigned char* dst;
    float scale;
    if (cid < A_CH8) {
        const int mi = (cid >> 9) & 3, s = cid >> 11;
        const int r  = s * 64 + mi * 16 + (lane & 15);      // anchor row = v*256+a
        src = X + ((size_t)((r & 255) * 8 + (r >> 8))) * FEAT + k;
        dst = Abuf + ((size_t)cid << 3);
        scale = EXP2K;
    } else {
        const int b = cid - A_CH8;
        const int ni = (b >> 9) & 3, p = b >> 11;
        const int col = p * 64 + ni * 16 + (lane & 15);     // class 0 skipped
        src = Q + ((size_t)(BANK + col)) * FEAT + k;
        dst = Bbuf + ((size_t)b << 3);
        scale = 1.0f;
    }
    float4_t v0 = *(const float4_t*)src;
    float4_t v1 = *(const float4_t*)(src + 4);
    *(uint2_t*)dst = pack8_fp8(v0, v1, scale);
}

// Pass 2 (separate kernel): per-class column sums of Q (f32), 16 m-chunks
// per class, atomicAdd into csum[c][k]. Q is L3-resident after pass0.
__global__ __launch_bounds__(256) void pass2_csum(
    const float* __restrict__ Q, float* __restrict__ csum)
{
    const int c = blockIdx.x >> 4;        // 0..17 -> class c+1
    const int i = blockIdx.x & 15;
    const int k = threadIdx.x;
    const float* base = Q + ((size_t)(c + 1) * BANK + (size_t)i * (BANK / CSPLIT)) * FEAT + k;
    float s = 0.0f;
    #pragma unroll 4
    for (int m = 0; m < BANK / CSPLIT; ++m) s += base[(size_t)m * FEAT];
    atomicAdd(&csum[c * FEAT + k], s);
}

// Pass 1: barrier-free streaming fp8 GEMM, 128 ROWS PER WAVE (halves B L2
// traffic vs R24; 16 MFMAs per B-fragment -> loads fully hidden), 4-panel
// slots, 2-deep ping-pong b0/b1. a[8][8]=128 + b 32 + acc 32 + rs 32 ~ 236
// regs < 256 cap at (128,2); measured residency was already 2 waves/SIMD.
__global__ __launch_bounds__(128, 2) void pass1_gemm(
    const unsigned char* __restrict__ Abuf,
    const unsigned char* __restrict__ Bbuf,
    float* __restrict__ partS)  // [NROWS][NSLOT2]
{
    // XCD-banded: xcd = bid&7 owns slots [xcd*18, xcd*18+18)
    const int bid = blockIdx.x;            // 0..1151
    const int xcd = bid & 7;
    const int j   = bid >> 3;              // 0..143
    const int t = threadIdx.x, lane = t & 63, w = t >> 6;   // w: 0..1
    const int u = j * 2 + w;               // 0..287 within xcd
    const int strip = u & 15;              // 128-row strip
    const int slot  = xcd * 18 + (u >> 4); // 0..143 (4 panels each)

    const int g = lane >> 4, ci = lane & 15;

    // ---- A fragments in registers (128 rows x 256 K fp8 = 128 VGPR) ----
    // Two consecutive 64-row pass0 strips: long idx = (2*strip + (mi>>2))*2048
    //                                               + (mi&3)*512 + ks*64 + lane.
    const long* AL = (const long*)Abuf;
    long a[8][8];
    #pragma unroll
    for (int mi = 0; mi < 8; ++mi)
        #pragma unroll
        for (int ks = 0; ks < 8; ++ks)
            a[mi][ks] = AL[(size_t)(2 * strip + (mi >> 2)) * 2048 + (mi & 3) * 512 + ks * 64 + lane];

    // slot's 4 panels contiguous: flat step s in [0,16), chunk = (s*8+ks)*64+lane
    const long* Bs = (const long*)(Bbuf + ((size_t)(slot * 4) << 14));

    float rs[8][4] = {};
    long b0[8], b1[8];

    #pragma unroll
    for (int ks = 0; ks < 8; ++ks)
        b0[ks] = Bs[ks * 64 + lane];                       // step 0

    #pragma unroll 1
    for (int s = 0; s < 8; ++s) {
        // issue step 2s+1 loads (fly under b0 compute)
        #pragma unroll
        for (int ks = 0; ks < 8; ++ks)
            b1[ks] = Bs[((size_t)(2 * s + 1) * 8 + ks) * 64 + lane];
        {
            f32x4 acc[8] = {};
            #pragma unroll
            for (int ks = 0; ks < 8; ++ks)
                #pragma unroll
                for (int mi = 0; mi < 8; ++mi)
                    acc[mi] = __builtin_amdgcn_mfma_f32_16x16x32_fp8_fp8(a[mi][ks], b0[ks], acc[mi], 0, 0, 0);
            #pragma unroll
            for (int mi = 0; mi < 8; ++mi)
                #pragma unroll
                for (int rj = 0; rj < 4; ++rj)
                    rs[mi][rj] += __builtin_amdgcn_exp2f(acc[mi][rj]);
        }
        // issue step 2s+2 loads (fly under b1 compute)
        if (s < 7) {
            #pragma unroll
            for (int ks = 0; ks < 8; ++ks)
                b0[ks] = Bs[((size_t)(2 * s + 2) * 8 + ks) * 64 + lane];
        }
        {
            f32x4 acc[8] = {};
            #pragma unroll
            for (int ks = 0; ks < 8; ++ks)
                #pragma unroll
                for (int mi = 0; mi < 8; ++mi)
                    acc[mi] = __builtin_amdgcn_mfma_f32_16x16x32_fp8_fp8(a[mi][ks], b1[ks], acc[mi], 0, 0, 0);
            #pragma unroll
            for (int mi = 0; mi < 8; ++mi)
                #pragma unroll
                for (int rj = 0; rj < 4; ++rj)
                    rs[mi][rj] += __builtin_amdgcn_exp2f(acc[mi][rj]);
        }
    }

    // ---- one DPP reduce + store block per wave ----
    #pragma unroll
    for (int mi = 0; mi < 8; ++mi)
        #pragma unroll
        for (int rj = 0; rj < 4; ++rj) {
            const float v = rowsum16(rs[mi][rj]);
            if (ci == 0)
                partS[(size_t)(strip * 128 + mi * 16 + g * 4 + rj) * NSLOT2 + slot] = v;
        }
}

// Pass 3: ONE WAVE PER ROW (512 blocks x 4 waves). partS[r][144] coalesced,
// E1 over the class's 8 slots; Lp via float4 X.csum dot; diag for class-1.
__global__ __launch_bounds__(256) void pass3_kernel(
    const int* __restrict__ y,
    const float* __restrict__ partS, const float* __restrict__ csum,
    const float* __restrict__ X, const float* __restrict__ Q,
    float* __restrict__ out)
{
    __shared__ float sh[4];
    const int t = threadIdx.x, lane = t & 63, w = t >> 6;
    const int r = blockIdx.x * 4 + w;
    const int c = y[r & 255];

    const float* ps = partS + (size_t)r * NSLOT2;
    float S = 0.0f, E1 = 0.0f;
    const int s0 = (c - 1) * 8, s1 = c * 8;
    #pragma unroll
    for (int i = 0; i < 3; ++i) {
        const int p = i * 64 + lane;
        if (p < NSLOT2) {
            const float v = ps[p];
            S += v;
            if (p >= s0 && p < s1) E1 += v;
        }
    }
    const float* Xrow = X + ((size_t)((r & 255) * 8 + (r >> 8))) * FEAT;
    const float4_t xv = ((const float4_t*)Xrow)[lane];
    const float4_t cv = ((const float4_t*)(csum + (size_t)(c - 1) * FEAT))[lane];
    float dot = xv.x * cv.x + xv.y * cv.y + xv.z * cv.z + xv.w * cv.w;
    if (c == 1) {
        const float4_t qv = ((const float4_t*)(Q + ((size_t)(BANK + r)) * FEAT))[lane];
        dot -= xv.x * qv.x + xv.y * qv.y + xv.z * qv.z + xv.w * qv.w;
    }
    #pragma unroll
    for (int mm = 1; mm < 64; mm <<= 1) {
        S   += __shfl_xor(S, mm);
        E1  += __shfl_xor(E1, mm);
        dot += __shfl_xor(dot, mm);
    }
    if (lane == 0) {
        const float m = (c == 1) ? 2047.0f : 2048.0f;
        const float neg = S - E1 + 2048.0f;
        sh[w] = __logf(neg) - 10.0f * dot / m;
    }
    __syncthreads();
    if (t == 0)
        atomicAdd(out, (sh[0] + sh[1] + sh[2] + sh[3]) * (1.0f / (float)NROWS));
}

extern "C" void kernel_launch(void* const* d_in, const int* in_sizes, int n_in,
                              void* d_out, int out_size, void* d_ws, size_t ws_size,
                              hipStream_t stream) {
    const float* X = (const float*)d_in[0];
    const int*   y = (const int*)d_in[1];
    const float* Q = (const float*)d_in[2];
    float* out   = (float*)d_out;
    float* partS = (float*)d_ws;                                // 2048*144 f32 (1.18 MB)
    float* csum  = partS + (size_t)NROWS * NSLOT2;              // 18*256 f32 (18 KB)
    unsigned char* Abuf = (unsigned char*)(csum + NCLS * FEAT); // 512 KB
    unsigned char* Bbuf = Abuf + ((size_t)A_CH8 << 3);          // 9.44 MB

    pass0_pack<<<dim3((TOT8 + 255) / 256), dim3(256), 0, stream>>>(X, Q, Abuf, Bbuf, csum, out);
    pass2_csum<<<dim3(NCLS * CSPLIT), dim3(256), 0, stream>>>(Q, csum);
    pass1_gemm<<<dim3(1152), dim3(128), 0, stream>>>(Abuf, Bbuf, partS);
    pass3_kernel<<<dim3(NROWS / 4), dim3(256), 0, stream>>>(y, partS, csum, X, Q, out);
}

// Round 28
// 64.328 us; speedup vs baseline: 1.0686x; 1.0686x over previous
//
#include <hip/hip_runtime.h>
#include <hip/hip_fp8.h>

typedef float  float4_t __attribute__((ext_vector_type(4)));
typedef unsigned int uint2_t __attribute__((ext_vector_type(2)));
typedef float  f32x4   __attribute__((ext_vector_type(4)));

#define FEAT   256
#define BANK   2048
#define NROWS  2048       // 256 anchors * 8 views
#define NPAN   576        // 64-col panels over 36864 cols
#define NSLOT2 144        // 4-panel slots (class-aligned: 32 % 4 == 0)
#define NCLS   18
#define CSPLIT 16         // m-chunks per class for csum atomics
#define EXP2K  14.4269504088896f   // 10*log2(e); A pre-scaled -> exp(10 dot)=exp2(acc)
#define A_CH8  65536      // A 8-byte chunks: 32 strips * 4 mi * 8 ks * 64 lanes
#define B_CH8  1179648    // B 8-byte chunks: 576 panels * 32 frags * 64 lanes
#define TOT8   (A_CH8 + B_CH8)

// 16-lane (DPP row) sum: every lane of each 16-lane group gets the group total.
__device__ inline float rowsum16(float x) {
    float t;
    asm("s_nop 1\n\tv_add_f32 %0, %1, %1 row_ror:1"  : "=v"(t) : "v"(x)); x = t;
    asm("s_nop 1\n\tv_add_f32 %0, %1, %1 row_ror:2"  : "=v"(t) : "v"(x)); x = t;
    asm("s_nop 1\n\tv_add_f32 %0, %1, %1 row_ror:4"  : "=v"(t) : "v"(x)); x = t;
    asm("s_nop 1\n\tv_add_f32 %0, %1, %1 row_ror:8"  : "=v"(t) : "v"(x)); x = t;
    return x;
}

// HW fp8 pair conversion: packs 8 floats -> 8 e4m3 bytes in 4 instructions.
__device__ inline uint2_t pack8_fp8(float4_t v0, float4_t v1, float scale) {
    int w0 = __builtin_amdgcn_cvt_pk_fp8_f32(v0.x * scale, v0.y * scale, 0, false);
    w0     = __builtin_amdgcn_cvt_pk_fp8_f32(v0.z * scale, v0.w * scale, w0, true);
    int w1 = __builtin_amdgcn_cvt_pk_fp8_f32(v1.x * scale, v1.y * scale, 0, false);
    w1     = __builtin_amdgcn_cvt_pk_fp8_f32(v1.z * scale, v1.w * scale, w1, true);
    uint2_t u = { (unsigned int)w0, (unsigned int)w1 };
    return u;
}

// Pass 0: fp32 -> fp8 e4m3 ONCE via v_cvt_pk_fp8_f32 (HW), MFMA fragment
// order; A pre-scaled by EXP2K (64-row strips). Zeroes out[0] and csum inline.
__global__ __launch_bounds__(256) void pass0_pack(
    const float* __restrict__ X,    // X_anchor [256][8][256]
    const float* __restrict__ Q,    // queue [19][2048][256]
    unsigned char* __restrict__ Abuf,
    unsigned char* __restrict__ Bbuf,
    float* __restrict__ csum,
    float* __restrict__ out)
{
    const int cid = blockIdx.x * 256 + threadIdx.x;
    if (cid == 0) out[0] = 0.0f;
    if (cid < NCLS * FEAT) csum[cid] = 0.0f;
    if (cid >= TOT8) return;
    const int lane = cid & 63;
    const int ks   = (cid >> 6) & 7;
    const int k    = ks * 32 + ((lane >> 4) << 3);
    const float* src;
    unsigned char* dst;
    float scale;
    if (cid < A_CH8) {
        const int mi = (cid >> 9) & 3, s = cid >> 11;
        const int r  = s * 64 + mi * 16 + (lane & 15);      // anchor row = v*256+a
        src = X + ((size_t)((r & 255) * 8 + (r >> 8))) * FEAT + k;
        dst = Abuf + ((size_t)cid << 3);
        scale = EXP2K;
    } else {
        const int b = cid - A_CH8;
        const int ni = (b >> 9) & 3, p = b >> 11;
        const int col = p * 64 + ni * 16 + (lane & 15);     // class 0 skipped
        src = Q + ((size_t)(BANK + col)) * FEAT + k;
        dst = Bbuf + ((size_t)b << 3);
        scale = 1.0f;
    }
    float4_t v0 = *(const float4_t*)src;
    float4_t v1 = *(const float4_t*)(src + 4);
    *(uint2_t*)dst = pack8_fp8(v0, v1, scale);
}

// Pass 2 (separate kernel): per-class column sums of Q (f32), 16 m-chunks
// per class, atomicAdd into csum[c][k]. Q is L3-resident after pass0.
__global__ __launch_bounds__(256) void pass2_csum(
    const float* __restrict__ Q, float* __restrict__ csum)
{
    const int c = blockIdx.x >> 4;        // 0..17 -> class c+1
    const int i = blockIdx.x & 15;
    const int k = threadIdx.x;
    const float* base = Q + ((size_t)(c + 1) * BANK + (size_t)i * (BANK / CSPLIT)) * FEAT + k;
    float s = 0.0f;
    #pragma unroll 4
    for (int m = 0; m < BANK / CSPLIT; ++m) s += base[(size_t)m * FEAT];
    atomicAdd(&csum[c * FEAT + k], s);
}

// Pass 1 (R24 exact, best measured: pass1 ~38 us, total 63.1): barrier-free
// streaming fp8 GEMM, 64 rows/wave, 4-panel slots, 2-DEEP PING-PONG on the
// 16-reg B fragment inside a rolled loop (8 iters x 2 steps): load(s+1)
// issues before compute(s) completes. Named b0/b1, ~72 regs at (128,3).
__global__ __launch_bounds__(128, 3) void pass1_gemm(
    const unsigned char* __restrict__ Abuf,
    const unsigned char* __restrict__ Bbuf,
    float* __restrict__ partS)  // [NROWS][NSLOT2]
{
    // XCD-banded: xcd = bid&7 owns slots [xcd*18, xcd*18+18)
    const int bid = blockIdx.x;            // 0..2303
    const int xcd = bid & 7;
    const int j   = bid >> 3;              // 0..287
    const int t = threadIdx.x, lane = t & 63, w = t >> 6;   // w: 0..1
    const int u = j * 2 + w;               // 0..575 within xcd
    const int strip = u & 31;              // 64-row strip
    const int slot  = xcd * 18 + (u >> 5); // 0..143 (4 panels each)

    const int g = lane >> 4, ci = lane & 15;

    // ---- A fragments in registers (64 rows x 256 K fp8) ----
    const long* Ap = (const long*)(Abuf + ((size_t)strip << 14));
    long a[4][8];
    #pragma unroll
    for (int mi = 0; mi < 4; ++mi)
        #pragma unroll
        for (int ks = 0; ks < 8; ++ks)
            a[mi][ks] = Ap[((mi << 3) | ks) * 64 + lane];

    // slot's 4 panels are contiguous: flat step s = pi*4+nn in [0,16),
    // chunk(long) index = (s*8 + ks)*64 + lane.
    const long* Bs = (const long*)(Bbuf + ((size_t)(slot * 4) << 14));

    float rs[4][4] = {};
    long b0[8], b1[8];

    #pragma unroll
    for (int ks = 0; ks < 8; ++ks)
        b0[ks] = Bs[ks * 64 + lane];                       // step 0

    #pragma unroll 1
    for (int s = 0; s < 8; ++s) {
        // issue step 2s+1 loads (fly under b0 compute)
        #pragma unroll
        for (int ks = 0; ks < 8; ++ks)
            b1[ks] = Bs[((size_t)(2 * s + 1) * 8 + ks) * 64 + lane];
        {
            f32x4 acc[4] = {};
            #pragma unroll
            for (int ks = 0; ks < 8; ++ks) {
                acc[0] = __builtin_amdgcn_mfma_f32_16x16x32_fp8_fp8(a[0][ks], b0[ks], acc[0], 0, 0, 0);
                acc[1] = __builtin_amdgcn_mfma_f32_16x16x32_fp8_fp8(a[1][ks], b0[ks], acc[1], 0, 0, 0);
                acc[2] = __builtin_amdgcn_mfma_f32_16x16x32_fp8_fp8(a[2][ks], b0[ks], acc[2], 0, 0, 0);
                acc[3] = __builtin_amdgcn_mfma_f32_16x16x32_fp8_fp8(a[3][ks], b0[ks], acc[3], 0, 0, 0);
            }
            #pragma unroll
            for (int mi = 0; mi < 4; ++mi)
                #pragma unroll
                for (int rj = 0; rj < 4; ++rj)
                    rs[mi][rj] += __builtin_amdgcn_exp2f(acc[mi][rj]);
        }
        // issue step 2s+2 loads (fly under b1 compute)
        if (s < 7) {
            #pragma unroll
            for (int ks = 0; ks < 8; ++ks)
                b0[ks] = Bs[((size_t)(2 * s + 2) * 8 + ks) * 64 + lane];
        }
        {
            f32x4 acc[4] = {};
            #pragma unroll
            for (int ks = 0; ks < 8; ++ks) {
                acc[0] = __builtin_amdgcn_mfma_f32_16x16x32_fp8_fp8(a[0][ks], b1[ks], acc[0], 0, 0, 0);
                acc[1] = __builtin_amdgcn_mfma_f32_16x16x32_fp8_fp8(a[1][ks], b1[ks], acc[1], 0, 0, 0);
                acc[2] = __builtin_amdgcn_mfma_f32_16x16x32_fp8_fp8(a[2][ks], b1[ks], acc[2], 0, 0, 0);
                acc[3] = __builtin_amdgcn_mfma_f32_16x16x32_fp8_fp8(a[3][ks], b1[ks], acc[3], 0, 0, 0);
            }
            #pragma unroll
            for (int mi = 0; mi < 4; ++mi)
                #pragma unroll
                for (int rj = 0; rj < 4; ++rj)
                    rs[mi][rj] += __builtin_amdgcn_exp2f(acc[mi][rj]);
        }
    }

    // ---- one DPP reduce + store block per wave ----
    #pragma unroll
    for (int mi = 0; mi < 4; ++mi)
        #pragma unroll
        for (int rj = 0; rj < 4; ++rj) {
            const float v = rowsum16(rs[mi][rj]);
            if (ci == 0)
                partS[(size_t)(strip * 64 + mi * 16 + g * 4 + rj) * NSLOT2 + slot] = v;
        }
}

// Pass 3: ONE WAVE PER ROW (512 blocks x 4 waves). partS[r][144] coalesced,
// E1 over the class's 8 slots; Lp via float4 X.csum dot; diag for class-1.
__global__ __launch_bounds__(256) void pass3_kernel(
    const int* __restrict__ y,
    const float* __restrict__ partS, const float* __restrict__ csum,
    const float* __restrict__ X, const float* __restrict__ Q,
    float* __restrict__ out)
{
    __shared__ float sh[4];
    const int t = threadIdx.x, lane = t & 63, w = t >> 6;
    const int r = blockIdx.x * 4 + w;
    const int c = y[r & 255];

    const float* ps = partS + (size_t)r * NSLOT2;
    float S = 0.0f, E1 = 0.0f;
    const int s0 = (c - 1) * 8, s1 = c * 8;
    #pragma unroll
    for (int i = 0; i < 3; ++i) {
        const int p = i * 64 + lane;
        if (p < NSLOT2) {
            const float v = ps[p];
            S += v;
            if (p >= s0 && p < s1) E1 += v;
        }
    }
    const float* Xrow = X + ((size_t)((r & 255) * 8 + (r >> 8))) * FEAT;
    const float4_t xv = ((const float4_t*)Xrow)[lane];
    const float4_t cv = ((const float4_t*)(csum + (size_t)(c - 1) * FEAT))[lane];
    float dot = xv.x * cv.x + xv.y * cv.y + xv.z * cv.z + xv.w * cv.w;
    if (c == 1) {
        const float4_t qv = ((const float4_t*)(Q + ((size_t)(BANK + r)) * FEAT))[lane];
        dot -= xv.x * qv.x + xv.y * qv.y + xv.z * qv.z + xv.w * qv.w;
    }
    #pragma unroll
    for (int mm = 1; mm < 64; mm <<= 1) {
        S   += __shfl_xor(S, mm);
        E1  += __shfl_xor(E1, mm);
        dot += __shfl_xor(dot, mm);
    }
    if (lane == 0) {
        const float m = (c == 1) ? 2047.0f : 2048.0f;
        const float neg = S - E1 + 2048.0f;
        sh[w] = __logf(neg) - 10.0f * dot / m;
    }
    __syncthreads();
    if (t == 0)
        atomicAdd(out, (sh[0] + sh[1] + sh[2] + sh[3]) * (1.0f / (float)NROWS));
}

extern "C" void kernel_launch(void* const* d_in, const int* in_sizes, int n_in,
                              void* d_out, int out_size, void* d_ws, size_t ws_size,
                              hipStream_t stream) {
    const float* X = (const float*)d_in[0];
    const int*   y = (const int*)d_in[1];
    const float* Q = (const float*)d_in[2];
    float* out   = (float*)d_out;
    float* partS = (float*)d_ws;                                // 2048*144 f32 (1.18 MB)
    float* csum  = partS + (size_t)NROWS * NSLOT2;              // 18*256 f32 (18 KB)
    unsigned char* Abuf = (unsigned char*)(csum + NCLS * FEAT); // 512 KB
    unsigned char* Bbuf = Abuf + ((size_t)A_CH8 << 3);          // 9.44 MB

    pass0_pack<<<dim3((TOT8 + 255) / 256), dim3(256), 0, stream>>>(X, Q, Abuf, Bbuf, csum, out);
    pass2_csum<<<dim3(NCLS * CSPLIT), dim3(256), 0, stream>>>(Q, csum);
    pass1_gemm<<<dim3(2304), dim3(128), 0, stream>>>(Abuf, Bbuf, partS);
    pass3_kernel<<<dim3(NROWS / 4), dim3(256), 0, stream>>>(y, partS, csum, X, Q, out);
}

// Round 29
// 61.761 us; speedup vs baseline: 1.1130x; 1.0416x over previous
//
#include <hip/hip_runtime.h>
#include <hip/hip_fp8.h>

typedef float  float4_t __attribute__((ext_vector_type(4)));
typedef unsigned int uint2_t __attribute__((ext_vector_type(2)));
typedef float  f32x4   __attribute__((ext_vector_type(4)));
typedef int    v8i     __attribute__((ext_vector_type(8)));

#define FEAT   256
#define BANK   2048
#define NROWS  2048       // 256 anchors * 8 views
#define NPAN   576        // 64-col panels over 36864 cols
#define NSLOT2 144        // 4-panel slots (class-aligned: 32 % 4 == 0)
#define NCLS   18
#define CSPLIT 16         // m-chunks per class for csum atomics
#define EXP2K  14.4269504088896f   // 10*log2(e); A pre-scaled -> exp(10 dot)=exp2(acc)
#define SC1    0x7F7F7F7F          // e8m0 scale bytes = 127 -> 1.0 (exact)
#define A_CH8  65536      // A 8-byte chunks: 32 strips * 4 mi * 8 ks * 64 lanes
#define B_CH8  1179648    // B 8-byte chunks: 576 panels * 32 frags * 64 lanes
#define TOT8   (A_CH8 + B_CH8)

// 16-lane (DPP row) sum: every lane of each 16-lane group gets the group total.
__device__ inline float rowsum16(float x) {
    float t;
    asm("s_nop 1\n\tv_add_f32 %0, %1, %1 row_ror:1"  : "=v"(t) : "v"(x)); x = t;
    asm("s_nop 1\n\tv_add_f32 %0, %1, %1 row_ror:2"  : "=v"(t) : "v"(x)); x = t;
    asm("s_nop 1\n\tv_add_f32 %0, %1, %1 row_ror:4"  : "=v"(t) : "v"(x)); x = t;
    asm("s_nop 1\n\tv_add_f32 %0, %1, %1 row_ror:8"  : "=v"(t) : "v"(x)); x = t;
    return x;
}

// HW fp8 pair conversion: packs 8 floats -> 8 e4m3 bytes in 4 instructions.
__device__ inline uint2_t pack8_fp8(float4_t v0, float4_t v1, float scale) {
    int w0 = __builtin_amdgcn_cvt_pk_fp8_f32(v0.x * scale, v0.y * scale, 0, false);
    w0     = __builtin_amdgcn_cvt_pk_fp8_f32(v0.z * scale, v0.w * scale, w0, true);
    int w1 = __builtin_amdgcn_cvt_pk_fp8_f32(v1.x * scale, v1.y * scale, 0, false);
    w1     = __builtin_amdgcn_cvt_pk_fp8_f32(v1.z * scale, v1.w * scale, w1, true);
    uint2_t u = { (unsigned int)w0, (unsigned int)w1 };
    return u;
}

// Pass 0 (R24 exact): fp32 -> fp8 e4m3 ONCE via v_cvt_pk_fp8_f32, MFMA
// fragment order; A pre-scaled by EXP2K (64-row strips). The per-lane k-map
// (k = ks*32 + (lane>>4)*8 + i) is a bijection used identically for A and B,
// so the K=128 scaled-MFMA consumes 4 consecutive chunks per operand half
// unchanged (dot over K is invariant to a shared k-permutation).
__global__ __launch_bounds__(256) void pass0_pack(
    const float* __restrict__ X,    // X_anchor [256][8][256]
    const float* __restrict__ Q,    // queue [19][2048][256]
    unsigned char* __restrict__ Abuf,
    unsigned char* __restrict__ Bbuf,
    float* __restrict__ csum,
    float* __restrict__ out)
{
    const int cid = blockIdx.x * 256 + threadIdx.x;
    if (cid == 0) out[0] = 0.0f;
    if (cid < NCLS * FEAT) csum[cid] = 0.0f;
    if (cid >= TOT8) return;
    const int lane = cid & 63;
    const int ks   = (cid >> 6) & 7;
    const int k    = ks * 32 + ((lane >> 4) << 3);
    const float* src;
    unsigned char* dst;
    float scale;
    if (cid < A_CH8) {
        const int mi = (cid >> 9) & 3, s = cid >> 11;
        const int r  = s * 64 + mi * 16 + (lane & 15);      // anchor row = v*256+a
        src = X + ((size_t)((r & 255) * 8 + (r >> 8))) * FEAT + k;
        dst = Abuf + ((size_t)cid << 3);
        scale = EXP2K;
    } else {
        const int b = cid - A_CH8;
        const int ni = (b >> 9) & 3, p = b >> 11;
        const int col = p * 64 + ni * 16 + (lane & 15);     // class 0 skipped
        src = Q + ((size_t)(BANK + col)) * FEAT + k;
        dst = Bbuf + ((size_t)b << 3);
        scale = 1.0f;
    }
    float4_t v0 = *(const float4_t*)src;
    float4_t v1 = *(const float4_t*)(src + 4);
    *(uint2_t*)dst = pack8_fp8(v0, v1, scale);
}

// Pass 2 (separate kernel): per-class column sums of Q (f32), 16 m-chunks
// per class, atomicAdd into csum[c][k]. Q is L3-resident after pass0.
__global__ __launch_bounds__(256) void pass2_csum(
    const float* __restrict__ Q, float* __restrict__ csum)
{
    const int c = blockIdx.x >> 4;        // 0..17 -> class c+1
    const int i = blockIdx.x & 15;
    const int k = threadIdx.x;
    const float* base = Q + ((size_t)(c + 1) * BANK + (size_t)i * (BANK / CSPLIT)) * FEAT + k;
    float s = 0.0f;
    #pragma unroll 4
    for (int m = 0; m < BANK / CSPLIT; ++m) s += base[(size_t)m * FEAT];
    atomicAdd(&csum[c * FEAT + k], s);
}

// Pass 1: R24 structure (barrier-free, 64 rows/wave, 4-panel slots, 2-deep
// ping-pong, 16 steps) with the MFMA block swapped to MX-scaled fp8
// (mfma_scale_f32_16x16x128_f8f6f4, all scales = 1.0): 8 K=128 MFMAs per
// step instead of 32 K=32 MFMAs -> ~2.3x less matrix-pipe time.
__global__ __launch_bounds__(128, 3) void pass1_gemm(
    const unsigned char* __restrict__ Abuf,
    const unsigned char* __restrict__ Bbuf,
    float* __restrict__ partS)  // [NROWS][NSLOT2]
{
    // XCD-banded: xcd = bid&7 owns slots [xcd*18, xcd*18+18)
    const int bid = blockIdx.x;            // 0..2303
    const int xcd = bid & 7;
    const int j   = bid >> 3;              // 0..287
    const int t = threadIdx.x, lane = t & 63, w = t >> 6;   // w: 0..1
    const int u = j * 2 + w;               // 0..575 within xcd
    const int strip = u & 31;              // 64-row strip
    const int slot  = xcd * 18 + (u >> 5); // 0..143 (4 panels each)

    const int g = lane >> 4, ci = lane & 15;

    union U8 { long l[8]; v8i v[2]; };

    // ---- A fragments in registers (64 rows x 256 K fp8) ----
    const long* Ap = (const long*)(Abuf + ((size_t)strip << 14));
    U8 a2[4];
    #pragma unroll
    for (int mi = 0; mi < 4; ++mi)
        #pragma unroll
        for (int ks = 0; ks < 8; ++ks)
            a2[mi].l[ks] = Ap[((mi << 3) | ks) * 64 + lane];

    // slot's 4 panels are contiguous: flat step s in [0,16),
    // chunk(long) index = s*512 + ks*64 + lane.
    const long* Bs = (const long*)(Bbuf + ((size_t)(slot * 4) << 14));

    float rs[4][4] = {};
    U8 b0, b1;

    #pragma unroll
    for (int ks = 0; ks < 8; ++ks)
        b0.l[ks] = Bs[ks * 64 + lane];                     // step 0

    #pragma unroll 1
    for (int s = 0; s < 8; ++s) {
        // issue step 2s+1 loads (fly under b0 compute)
        #pragma unroll
        for (int ks = 0; ks < 8; ++ks)
            b1.l[ks] = Bs[((size_t)(2 * s + 1) * 512) + ks * 64 + lane];
        {
            f32x4 acc[4] = {};
            #pragma unroll
            for (int kh = 0; kh < 2; ++kh)
                #pragma unroll
                for (int mi = 0; mi < 4; ++mi)
                    acc[mi] = __builtin_amdgcn_mfma_scale_f32_16x16x128_f8f6f4(
                        a2[mi].v[kh], b0.v[kh], acc[mi], 0, 0, 0, SC1, 0, SC1);
            #pragma unroll
            for (int mi = 0; mi < 4; ++mi)
                #pragma unroll
                for (int rj = 0; rj < 4; ++rj)
                    rs[mi][rj] += __builtin_amdgcn_exp2f(acc[mi][rj]);
        }
        // issue step 2s+2 loads (fly under b1 compute)
        if (s < 7) {
            #pragma unroll
            for (int ks = 0; ks < 8; ++ks)
                b0.l[ks] = Bs[((size_t)(2 * s + 2) * 512) + ks * 64 + lane];
        }
        {
            f32x4 acc[4] = {};
            #pragma unroll
            for (int kh = 0; kh < 2; ++kh)
                #pragma unroll
                for (int mi = 0; mi < 4; ++mi)
                    acc[mi] = __builtin_amdgcn_mfma_scale_f32_16x16x128_f8f6f4(
                        a2[mi].v[kh], b1.v[kh], acc[mi], 0, 0, 0, SC1, 0, SC1);
            #pragma unroll
            for (int mi = 0; mi < 4; ++mi)
                #pragma unroll
                for (int rj = 0; rj < 4; ++rj)
                    rs[mi][rj] += __builtin_amdgcn_exp2f(acc[mi][rj]);
        }
    }

    // ---- one DPP reduce + store block per wave ----
    #pragma unroll
    for (int mi = 0; mi < 4; ++mi)
        #pragma unroll
        for (int rj = 0; rj < 4; ++rj) {
            const float v = rowsum16(rs[mi][rj]);
            if (ci == 0)
                partS[(size_t)(strip * 64 + mi * 16 + g * 4 + rj) * NSLOT2 + slot] = v;
        }
}

// Pass 3: ONE WAVE PER ROW (512 blocks x 4 waves). partS[r][144] coalesced,
// E1 over the class's 8 slots; Lp via float4 X.csum dot; diag for class-1.
__global__ __launch_bounds__(256) void pass3_kernel(
    const int* __restrict__ y,
    const float* __restrict__ partS, const float* __restrict__ csum,
    const float* __restrict__ X, const float* __restrict__ Q,
    float* __restrict__ out)
{
    __shared__ float sh[4];
    const int t = threadIdx.x, lane = t & 63, w = t >> 6;
    const int r = blockIdx.x * 4 + w;
    const int c = y[r & 255];

    const float* ps = partS + (size_t)r * NSLOT2;
    float S = 0.0f, E1 = 0.0f;
    const int s0 = (c - 1) * 8, s1 = c * 8;
    #pragma unroll
    for (int i = 0; i < 3; ++i) {
        const int p = i * 64 + lane;
        if (p < NSLOT2) {
            const float v = ps[p];
            S += v;
            if (p >= s0 && p < s1) E1 += v;
        }
    }
    const float* Xrow = X + ((size_t)((r & 255) * 8 + (r >> 8))) * FEAT;
    const float4_t xv = ((const float4_t*)Xrow)[lane];
    const float4_t cv = ((const float4_t*)(csum + (size_t)(c - 1) * FEAT))[lane];
    float dot = xv.x * cv.x + xv.y * cv.y + xv.z * cv.z + xv.w * cv.w;
    if (c == 1) {
        const float4_t qv = ((const float4_t*)(Q + ((size_t)(BANK + r)) * FEAT))[lane];
        dot -= xv.x * qv.x + xv.y * qv.y + xv.z * qv.z + xv.w * qv.w;
    }
    #pragma unroll
    for (int mm = 1; mm < 64; mm <<= 1) {
        S   += __shfl_xor(S, mm);
        E1  += __shfl_xor(E1, mm);
        dot += __shfl_xor(dot, mm);
    }
    if (lane == 0) {
        const float m = (c == 1) ? 2047.0f : 2048.0f;
        const float neg = S - E1 + 2048.0f;
        sh[w] = __logf(neg) - 10.0f * dot / m;
    }
    __syncthreads();
    if (t == 0)
        atomicAdd(out, (sh[0] + sh[1] + sh[2] + sh[3]) * (1.0f / (float)NROWS));
}

extern "C" void kernel_launch(void* const* d_in, const int* in_sizes, int n_in,
                              void* d_out, int out_size, void* d_ws, size_t ws_size,
                              hipStream_t stream) {
    const float* X = (const float*)d_in[0];
    const int*   y = (const int*)d_in[1];
    const float* Q = (const float*)d_in[2];
    float* out   = (float*)d_out;
    float* partS = (float*)d_ws;                                // 2048*144 f32 (1.18 MB)
    float* csum  = partS + (size_t)NROWS * NSLOT2;              // 18*256 f32 (18 KB)
    unsigned char* Abuf = (unsigned char*)(csum + NCLS * FEAT); // 512 KB
    unsigned char* Bbuf = Abuf + ((size_t)A_CH8 << 3);          // 9.44 MB

    pass0_pack<<<dim3((TOT8 + 255) / 256), dim3(256), 0, stream>>>(X, Q, Abuf, Bbuf, csum, out);
    pass2_csum<<<dim3(NCLS * CSPLIT), dim3(256), 0, stream>>>(Q, csum);
    pass1_gemm<<<dim3(2304), dim3(128), 0, stream>>>(Abuf, Bbuf, partS);
    pass3_kernel<<<dim3(NROWS / 4), dim3(256), 0, stream>>>(y, partS, csum, X, Q, out);
}